// Round 4
// baseline (1936.096 us; speedup 1.0000x reference)
//
#include <hip/hip_runtime.h>
#include <stdint.h>

typedef unsigned short u16;
typedef unsigned char u8;
typedef unsigned int u32;

#define LOG2E 1.4426950408889634f
#define LN2   0.6931471805599453f

__device__ __forceinline__ float exp2_(float x){ return __builtin_amdgcn_exp2f(x); }
__device__ __forceinline__ float log2_(float x){ return __builtin_amdgcn_logf(x); }
__device__ __forceinline__ float bflo(u32 u){ return __uint_as_float(u << 16); }
__device__ __forceinline__ float bfhi(u32 u){ return __uint_as_float(u & 0xffff0000u); }
__device__ __forceinline__ u16 f2bf(float f){
  u32 u = __float_as_uint(f);
  return (u16)((u + 0x7fffu + ((u >> 16) & 1u)) >> 16);
}
// bool input read: stride 1 (u8 bools) or 4 (int32 bools, LE low byte)
__device__ __forceinline__ int rdmask(const u8* p, int i, int st){ return (int)p[(size_t)i * st]; }

// ---------------- detect bool dtype: crf_mask[0,:] is all-true ----------------
__global__ void k_detect(const u32* __restrict__ cmask, int* __restrict__ flags) {
  flags[0] = (cmask[0] == 0x01010101u) ? 1 : 4;
}

// ---------------- normalize rows (txt & img) to bf16 ----------------
__global__ __launch_bounds__(256) void k_normalize(const float* __restrict__ txt,
                                                   const float* __restrict__ img,
                                                   u16* __restrict__ xh, u16* __restrict__ yh) {
  int row = blockIdx.x * 4 + (threadIdx.x >> 6);
  int l = threadIdx.x & 63;
  const float* src; u16* dst;
  if (row < 32768) { src = txt + (size_t)row * 768; dst = xh + (size_t)row * 768; }
  else { int r2 = row - 32768; src = img + (size_t)r2 * 768; dst = yh + (size_t)r2 * 768; }
  float v[12]; float ss = 0.f;
  #pragma unroll
  for (int s = 0; s < 12; ++s) { v[s] = src[l + (s << 6)]; ss = fmaf(v[s], v[s], ss); }
  #pragma unroll
  for (int off = 32; off; off >>= 1) ss += __shfl_xor(ss, off);
  float sc = 1.0f / fmaxf(sqrtf(ss), 1e-5f);
  #pragma unroll
  for (int s = 0; s < 12; ++s) dst[l + (s << 6)] = f2bf(v[s] * sc);
}

// ---------------- cost matrix: Ct2[b][n][m] = (log2e/beta)*(1 - yh_n . xh_m), masked -> 3e4 ----
typedef __attribute__((ext_vector_type(8))) short short8;
typedef __attribute__((ext_vector_type(4))) float f32x4;

__global__ __launch_bounds__(256) void k_cost_gemm(const u16* __restrict__ xh, const u16* __restrict__ yh,
                                                   const u8* __restrict__ xpad, const u8* __restrict__ ypad,
                                                   const int* __restrict__ flags,
                                                   u16* __restrict__ Ct2) {
  __shared__ u16 As[128 * 64];
  __shared__ u16 Bs[128 * 64];
  int st = flags[0];
  int bt = blockIdx.x;
  int b = bt >> 4;
  int tile = bt & 15;
  int tn = tile >> 2, tm = tile & 3;
  const u16* Ab = yh + ((size_t)b * 512 + tn * 128) * 768;
  const u16* Bb = xh + ((size_t)b * 512 + tm * 128) * 768;
  int tid = threadIdx.x;
  int w = tid >> 6, l = tid & 63;
  int wr = (w >> 1) << 6, wc = (w & 1) << 6;
  f32x4 acc[4][4] = {};
  for (int k0 = 0; k0 < 768; k0 += 64) {
    #pragma unroll
    for (int q = 0; q < 4; ++q) {
      int slot = (q << 8) + tid;
      int row = slot >> 3, col = (slot & 7) << 3;
      uint4 va = *(const uint4*)(Ab + row * 768 + k0 + col);
      uint4 vb = *(const uint4*)(Bb + row * 768 + k0 + col);
      *(uint4*)((char*)As + slot * 16) = va;
      *(uint4*)((char*)Bs + slot * 16) = vb;
    }
    __syncthreads();
    #pragma unroll
    for (int kk = 0; kk < 64; kk += 32) {
      int cb = (kk + ((l >> 4) << 3)) * 2;
      short8 a[4], bb[4];
      #pragma unroll
      for (int i = 0; i < 4; ++i)
        a[i] = *(const short8*)((const char*)As + (wr + (i << 4) + (l & 15)) * 128 + cb);
      #pragma unroll
      for (int j = 0; j < 4; ++j)
        bb[j] = *(const short8*)((const char*)Bs + (wc + (j << 4) + (l & 15)) * 128 + cb);
      #pragma unroll
      for (int i = 0; i < 4; ++i)
        #pragma unroll
        for (int j = 0; j < 4; ++j)
          acc[i][j] = __builtin_amdgcn_mfma_f32_16x16x32_bf16(a[i], bb[j], acc[i][j], 0, 0, 0);
    }
    __syncthreads();
  }
  int n0 = (tn << 7) + wr, m0 = (tm << 7) + wc;
  #pragma unroll
  for (int i = 0; i < 4; ++i) {
    #pragma unroll
    for (int j = 0; j < 4; ++j) {
      int m = m0 + (j << 4) + (l & 15);
      int xpm = rdmask(xpad, b * 512 + m, st);
      #pragma unroll
      for (int r = 0; r < 4; ++r) {
        int n = n0 + (i << 4) + ((l >> 4) << 2) + r;
        float v = 2.8853901f * (1.0f - acc[i][j][r]);
        if (xpm | rdmask(ypad, b * 512 + n, st)) v = 30000.0f;
        Ct2[((size_t)(b * 512 + n) << 9) + m] = f2bf(v);
      }
    }
  }
}

// ---------------- cross-block per-batch barrier (agent-scope) ----------------
__device__ __forceinline__ void batch_barrier(int* cnt, int target) {
  __syncthreads();
  if (threadIdx.x == 0) {
    __hip_atomic_fetch_add(cnt, 1, __ATOMIC_RELEASE, __HIP_MEMORY_SCOPE_AGENT);
    while (__hip_atomic_load(cnt, __ATOMIC_ACQUIRE, __HIP_MEMORY_SCOPE_AGENT) < target)
      __builtin_amdgcn_s_sleep(1);
  }
  __syncthreads();
}

// ---------------- IPOT in log2 space, 8 blocks per batch, 2 blocks/CU ----------------
// block bid: b = bid>>3, owns rows [p*64, p*64+64) of the 512x512 Ct2[b].
// Exponent folding: pass1 weight sig[m] folded into lw[m] = lv_old + 2*log2(sg).
__global__ __launch_bounds__(1024, 8) void k_ipot8(const u16* __restrict__ Ct2,
                                                   const u8* __restrict__ xpad, const u8* __restrict__ ypad,
                                                   const int* __restrict__ flags,
                                                   int* __restrict__ gcount, float* __restrict__ c_part,
                                                   float* __restrict__ fin_part,
                                                   float* __restrict__ ot) {
  int bid = blockIdx.x;
  int b = bid >> 3, p = bid & 7;
  int tid = threadIdx.x;
  int w = tid >> 6, l = tid & 63;
  int st = flags[0];
  __shared__ __align__(16) float lv[512], lw[512], xmk[512], ymk[512];
  __shared__ __align__(16) float lu[64], rr[64];
  __shared__ __align__(16) float cpart[16][512];
  __shared__ float redw[16];
  __shared__ int cnti[2];
  if (tid < 2) cnti[tid] = 0;
  __syncthreads();
  if (tid < 512) {
    int xp = rdmask(xpad, (b << 9) + tid, st) ? 1 : 0;
    int yp = rdmask(ypad, (b << 9) + tid, st) ? 1 : 0;
    xmk[tid] = xp ? 1e4f : 0.f;
    ymk[tid] = yp ? 1e4f : 0.f;
    lv[tid] = 0.f;
    atomicAdd(&cnti[0], 1 - xp);
    atomicAdd(&cnti[1], 1 - yp);
  }
  if (tid < 64) lu[tid] = 0.f;
  __syncthreads();
  float xl = (float)cnti[0], yl = (float)cnti[1];
  // initial sigma: 1/xl (unmasked) or 0 (masked) -> lw = log2(sigma)
  if (tid < 512) lw[tid] = (xmk[tid] > 0.f) ? -1e30f : -log2_(xl);
  __syncthreads();
  const int base_n = p << 6;
  const u16* Cb = Ct2 + ((size_t)b << 18) + ((size_t)base_n << 9);
  int* cnt_b = gcount + (b << 6);
  float* cp_b = c_part + ((size_t)b << 13);     // per batch: 2 parities * 8 parts * 512

  for (int it = 1; it <= 50; ++it) {
    float nt1 = -(float)it;
    int par = it & 1;
    float lvl[8], lwl[8];
    {
      const float4* p1 = (const float4*)&lv[l << 3];
      const float4* p2 = (const float4*)&lw[l << 3];
      float4 a0 = p1[0], a1 = p1[1], c0 = p2[0], c1 = p2[1];
      lvl[0]=a0.x; lvl[1]=a0.y; lvl[2]=a0.z; lvl[3]=a0.w;
      lvl[4]=a1.x; lvl[5]=a1.y; lvl[6]=a1.z; lvl[7]=a1.w;
      lwl[0]=c0.x; lwl[1]=c0.y; lwl[2]=c0.z; lwl[3]=c0.w;
      lwl[4]=c1.x; lwl[5]=c1.y; lwl[6]=c1.z; lwl[7]=c1.w;
    }
    // pass 1: rr[n] = sum_m exp2(lu[n]+lw[m]-t*C)   (own 64 rows)
    #pragma unroll
    for (int q = 0; q < 4; ++q) {
      int nl = (q << 4) | w;
      float lun = lu[nl];
      float bj[8];
      #pragma unroll
      for (int j = 0; j < 8; ++j) bj[j] = lun + lwl[j];
      const uint4 cv = *(const uint4*)(Cb + ((size_t)nl << 9) + (l << 3));
      float acc = 0.f;
      acc += exp2_(fmaf(bflo(cv.x), nt1, bj[0]));
      acc += exp2_(fmaf(bfhi(cv.x), nt1, bj[1]));
      acc += exp2_(fmaf(bflo(cv.y), nt1, bj[2]));
      acc += exp2_(fmaf(bfhi(cv.y), nt1, bj[3]));
      acc += exp2_(fmaf(bflo(cv.z), nt1, bj[4]));
      acc += exp2_(fmaf(bfhi(cv.z), nt1, bj[5]));
      acc += exp2_(fmaf(bflo(cv.w), nt1, bj[6]));
      acc += exp2_(fmaf(bfhi(cv.w), nt1, bj[7]));
      #pragma unroll
      for (int off = 32; off; off >>= 1) acc += __shfl_down(acc, off);
      if (l == 0) rr[nl] = acc;
    }
    __syncthreads();
    if (tid < 64) {
      float dv = 1.0f / fmaf(yl, rr[tid], ymk[base_n + tid]);
      lu[tid] += log2_(dv);   // fold delta into lu
    }
    __syncthreads();
    // pass 2: partial c[m] = sum_{own n} exp2(lu'[n]+lv[m]-t*C)
    float ca[8] = {0,0,0,0,0,0,0,0};
    #pragma unroll
    for (int q = 0; q < 4; ++q) {
      int nl = (q << 4) | w;
      float lun = lu[nl];
      float bj[8];
      #pragma unroll
      for (int j = 0; j < 8; ++j) bj[j] = lun + lvl[j];
      const uint4 cv = *(const uint4*)(Cb + ((size_t)nl << 9) + (l << 3));
      ca[0] += exp2_(fmaf(bflo(cv.x), nt1, bj[0]));
      ca[1] += exp2_(fmaf(bfhi(cv.x), nt1, bj[1]));
      ca[2] += exp2_(fmaf(bflo(cv.y), nt1, bj[2]));
      ca[3] += exp2_(fmaf(bfhi(cv.y), nt1, bj[3]));
      ca[4] += exp2_(fmaf(bflo(cv.z), nt1, bj[4]));
      ca[5] += exp2_(fmaf(bfhi(cv.z), nt1, bj[5]));
      ca[6] += exp2_(fmaf(bflo(cv.w), nt1, bj[6]));
      ca[7] += exp2_(fmaf(bfhi(cv.w), nt1, bj[7]));
    }
    {
      float4* dp = (float4*)&cpart[w][l << 3];
      float4 v0, v1;
      v0.x=ca[0]; v0.y=ca[1]; v0.z=ca[2]; v0.w=ca[3];
      v1.x=ca[4]; v1.y=ca[5]; v1.z=ca[6]; v1.w=ca[7];
      dp[0] = v0; dp[1] = v1;
    }
    __syncthreads();
    float* slot = cp_b + (par << 12) + (p << 9);
    if (tid < 512) {
      float s = 0.f;
      #pragma unroll
      for (int ww = 0; ww < 16; ++ww) s += cpart[ww][tid];
      __hip_atomic_store(&slot[tid], s, __ATOMIC_RELAXED, __HIP_MEMORY_SCOPE_AGENT);
    }
    batch_barrier(&cnt_b[it - 1], 8);
    if (tid < 512) {
      const float* base = cp_b + (par << 12);
      float s = 0.f;
      #pragma unroll
      for (int pp = 0; pp < 8; ++pp)
        s += __hip_atomic_load(&base[(pp << 9) + tid], __ATOMIC_RELAXED, __HIP_MEMORY_SCOPE_AGENT);
      float sg = 1.0f / fmaf(xl, s, xmk[tid]);
      float lg = log2_(sg);
      float lvo = lv[tid];
      lw[tid] = lvo + 2.0f * lg;   // lv_new + log2(sig_new)
      lv[tid] = lvo + lg;
    }
    __syncthreads();
  }
  // final: partial dist = sum_{own n} exp2(lu+lv-50*Ct2) * (Ct2 * beta*ln2)
  float lvl[8];
  {
    const float4* p1 = (const float4*)&lv[l << 3];
    float4 a0 = p1[0], a1 = p1[1];
    lvl[0]=a0.x; lvl[1]=a0.y; lvl[2]=a0.z; lvl[3]=a0.w;
    lvl[4]=a1.x; lvl[5]=a1.y; lvl[6]=a1.z; lvl[7]=a1.w;
  }
  float accT = 0.f;
  #pragma unroll
  for (int q = 0; q < 4; ++q) {
    int nl = (q << 4) | w;
    float lun = lu[nl];
    float bj[8];
    #pragma unroll
    for (int j = 0; j < 8; ++j) bj[j] = lun + lvl[j];
    const uint4 cv = *(const uint4*)(Cb + ((size_t)nl << 9) + (l << 3));
    float rp = 0.f, c0;
    c0 = bflo(cv.x); rp = fmaf(exp2_(fmaf(c0, -50.f, bj[0])), c0, rp);
    c0 = bfhi(cv.x); rp = fmaf(exp2_(fmaf(c0, -50.f, bj[1])), c0, rp);
    c0 = bflo(cv.y); rp = fmaf(exp2_(fmaf(c0, -50.f, bj[2])), c0, rp);
    c0 = bfhi(cv.y); rp = fmaf(exp2_(fmaf(c0, -50.f, bj[3])), c0, rp);
    c0 = bflo(cv.z); rp = fmaf(exp2_(fmaf(c0, -50.f, bj[4])), c0, rp);
    c0 = bfhi(cv.z); rp = fmaf(exp2_(fmaf(c0, -50.f, bj[5])), c0, rp);
    c0 = bflo(cv.w); rp = fmaf(exp2_(fmaf(c0, -50.f, bj[6])), c0, rp);
    c0 = bfhi(cv.w); rp = fmaf(exp2_(fmaf(c0, -50.f, bj[7])), c0, rp);
    accT += rp;
  }
  #pragma unroll
  for (int off = 32; off; off >>= 1) accT += __shfl_down(accT, off);
  if (l == 0) redw[w] = accT;
  __syncthreads();
  if (tid == 0) {
    float s = 0.f;
    #pragma unroll
    for (int ww = 0; ww < 16; ++ww) s += redw[ww];
    __hip_atomic_store(&fin_part[(b << 3) + p], s, __ATOMIC_RELAXED, __HIP_MEMORY_SCOPE_AGENT);
  }
  batch_barrier(&cnt_b[50], 8);
  if (p == 0 && tid == 0) {
    float s = 0.f;
    #pragma unroll
    for (int pp = 0; pp < 8; ++pp)
      s += __hip_atomic_load(&fin_part[(b << 3) + pp], __ATOMIC_RELAXED, __HIP_MEMORY_SCOPE_AGENT);
    ot[b] = s * 0.34657359f;  // beta * ln2
  }
}

// ---------------- CRF llh: one block (1 wave) per batch ----------------
__global__ __launch_bounds__(64) void k_crf(const float* __restrict__ emis, const int* __restrict__ tags,
                                            const u8* __restrict__ mask, const int* __restrict__ flags,
                                            const float* __restrict__ startT, const float* __restrict__ endT,
                                            const float* __restrict__ trans, float* __restrict__ llh) {
  int b = blockIdx.x;
  int k = threadIdx.x;
  int st = flags[0];
  __shared__ float tr[441];
  for (int i = k; i < 441; i += 64) tr[i] = trans[i];
  __syncthreads();
  // numerator (parallel over t)
  float accs = 0.f; int cnt = 0;
  for (int t = k; t < 512; t += 64) {
    int mt = rdmask(mask, (t << 6) + b, st);
    cnt += mt;
    int tg = tags[(t << 6) + b];
    if (t == 0) {
      accs += startT[tg] + emis[(size_t)b * 21 + tg];
    } else if (mt) {
      int tgp = tags[((t - 1) << 6) + b];
      accs += tr[tgp * 21 + tg] + emis[((size_t)((t << 6) + b)) * 21 + tg];
    }
  }
  #pragma unroll
  for (int off = 32; off; off >>= 1) { accs += __shfl_down(accs, off); cnt += __shfl_down(cnt, off); }
  float numer = 0.f;
  if (k == 0) {
    int last = tags[((cnt - 1) << 6) + b];
    numer = accs + endT[last];
  }
  // forward recursion (lanes 0..20 hold states)
  int kc = (k < 21) ? k : 20;
  float s = startT[kc] + emis[(size_t)b * 21 + kc];
  for (int t = 1; t < 512; ++t) {
    float z[21];
    float zmax = -3.0e38f;
    #pragma unroll
    for (int j = 0; j < 21; ++j) {
      float sj = __shfl(s, j);
      z[j] = sj + tr[j * 21 + kc];
      zmax = fmaxf(zmax, z[j]);
    }
    float sum = 0.f;
    #pragma unroll
    for (int j = 0; j < 21; ++j) sum += exp2_((z[j] - zmax) * LOG2E);
    float ns = zmax + log2_(sum) * LN2 + emis[((size_t)((t << 6) + b)) * 21 + kc];
    s = rdmask(mask, (t << 6) + b, st) ? ns : s;
  }
  float f = (k < 21) ? (s + endT[kc]) : -3.0e38f;
  float m = f;
  #pragma unroll
  for (int off = 32; off; off >>= 1) m = fmaxf(m, __shfl_xor(m, off));
  float sum = (k < 21) ? exp2_((f - m) * LOG2E) : 0.f;
  #pragma unroll
  for (int off = 32; off; off >>= 1) sum += __shfl_xor(sum, off);
  float denom = m + log2_(sum) * LN2;
  if (k == 0) llh[b] = numer - denom;
}

// ---------------- finalize: out = sum_b (ot[b] - llh[b]) ----------------
__global__ __launch_bounds__(64) void k_finalize(const float* __restrict__ llh, const float* __restrict__ ot,
                                                 float* __restrict__ out) {
  int l = threadIdx.x;
  float v = ot[l] - llh[l];
  #pragma unroll
  for (int off = 32; off; off >>= 1) v += __shfl_down(v, off);
  if (l == 0) out[0] = v;
}

extern "C" void kernel_launch(void* const* d_in, const int* in_sizes, int n_in,
                              void* d_out, int out_size, void* d_ws, size_t ws_size,
                              hipStream_t stream) {
  const float* emis  = (const float*)d_in[0];
  const float* txt   = (const float*)d_in[1];
  const float* img   = (const float*)d_in[2];
  const float* startT= (const float*)d_in[3];
  const float* endT  = (const float*)d_in[4];
  const float* trans = (const float*)d_in[5];
  const int*  tags   = (const int*)d_in[6];
  const u8* cmask = (const u8*)d_in[7];
  const u8* xpad  = (const u8*)d_in[8];
  const u8* ypad  = (const u8*)d_in[9];
  char* wsb = (char*)d_ws;
  u16* xh  = (u16*)wsb;                          // 50331648 B (dead after gemm)
  u16* yh  = (u16*)(wsb + 50331648ll);           // 50331648 B (dead after gemm)
  u16* Ct2 = (u16*)(wsb + 100663296ll);          // 33554432 B
  float* ot    = (float*)(wsb + 134217728ll);    // 64 f32
  float* llh   = ot + 64;                        // 64 f32
  int*  flags  = (int*)(llh + 64);
  // ipot scratch aliases the dead xh region (memset AFTER gemm):
  int*  gcount  = (int*)wsb;                     // 64*64 ints = 16384 B
  float* c_part = (float*)(wsb + 16384ll);       // 64*2*8*512 f32 = 2 MB
  float* fin_part=(float*)(wsb + 16384ll + 2097152ll); // 64*8 f32
  float* out = (float*)d_out;

  hipLaunchKernelGGL(k_detect, dim3(1), dim3(1), 0, stream, (const u32*)cmask, flags);
  hipLaunchKernelGGL(k_normalize, dim3(16384), dim3(256), 0, stream, txt, img, xh, yh);
  hipLaunchKernelGGL(k_cost_gemm, dim3(1024), dim3(256), 0, stream, xh, yh, xpad, ypad, flags, Ct2);
  hipLaunchKernelGGL(k_crf, dim3(64), dim3(64), 0, stream, emis, tags, cmask, flags, startT, endT, trans, llh);
  hipMemsetAsync(gcount, 0, 64 * 64 * sizeof(int), stream);
  hipLaunchKernelGGL(k_ipot8, dim3(512), dim3(1024), 0, stream, Ct2, xpad, ypad, flags, gcount, c_part, fin_part, ot);
  hipLaunchKernelGGL(k_finalize, dim3(1), dim3(64), 0, stream, llh, ot, out);
}

// Round 5
// 1034.385 us; speedup vs baseline: 1.8717x; 1.8717x over previous
//
#include <hip/hip_runtime.h>
#include <stdint.h>

typedef unsigned short u16;
typedef unsigned char u8;
typedef unsigned int u32;

#define LOG2E 1.4426950408889634f
#define LN2   0.6931471805599453f

__device__ __forceinline__ float exp2_(float x){ return __builtin_amdgcn_exp2f(x); }
__device__ __forceinline__ float log2_(float x){ return __builtin_amdgcn_logf(x); }
__device__ __forceinline__ float bflo(u32 u){ return __uint_as_float(u << 16); }
__device__ __forceinline__ float bfhi(u32 u){ return __uint_as_float(u & 0xffff0000u); }
__device__ __forceinline__ u16 f2bf(float f){
  u32 u = __float_as_uint(f);
  return (u16)((u + 0x7fffu + ((u >> 16) & 1u)) >> 16);
}
// bool input read: stride 1 (u8 bools) or 4 (int32 bools, LE low byte)
__device__ __forceinline__ int rdmask(const u8* p, int i, int st){ return (int)p[(size_t)i * st]; }

// ---------------- detect bool dtype: crf_mask[0,:] is all-true ----------------
__global__ void k_detect(const u32* __restrict__ cmask, int* __restrict__ flags) {
  flags[0] = (cmask[0] == 0x01010101u) ? 1 : 4;
}

// ---------------- normalize rows (txt & img) to bf16 ----------------
__global__ __launch_bounds__(256) void k_normalize(const float* __restrict__ txt,
                                                   const float* __restrict__ img,
                                                   u16* __restrict__ xh, u16* __restrict__ yh) {
  int row = blockIdx.x * 4 + (threadIdx.x >> 6);
  int l = threadIdx.x & 63;
  const float* src; u16* dst;
  if (row < 32768) { src = txt + (size_t)row * 768; dst = xh + (size_t)row * 768; }
  else { int r2 = row - 32768; src = img + (size_t)r2 * 768; dst = yh + (size_t)r2 * 768; }
  float v[12]; float ss = 0.f;
  #pragma unroll
  for (int s = 0; s < 12; ++s) { v[s] = src[l + (s << 6)]; ss = fmaf(v[s], v[s], ss); }
  #pragma unroll
  for (int off = 32; off; off >>= 1) ss += __shfl_xor(ss, off);
  float sc = 1.0f / fmaxf(sqrtf(ss), 1e-5f);
  #pragma unroll
  for (int s = 0; s < 12; ++s) dst[l + (s << 6)] = f2bf(v[s] * sc);
}

// ---------------- cost matrix: Ct2[b][n][m] = (log2e/beta)*(1 - yh_n . xh_m), masked -> 3e4 ----
typedef __attribute__((ext_vector_type(8))) short short8;
typedef __attribute__((ext_vector_type(4))) float f32x4;

__global__ __launch_bounds__(256) void k_cost_gemm(const u16* __restrict__ xh, const u16* __restrict__ yh,
                                                   const u8* __restrict__ xpad, const u8* __restrict__ ypad,
                                                   const int* __restrict__ flags,
                                                   u16* __restrict__ Ct2) {
  __shared__ u16 As[128 * 64];
  __shared__ u16 Bs[128 * 64];
  int st = flags[0];
  int bt = blockIdx.x;
  int b = bt >> 4;
  int tile = bt & 15;
  int tn = tile >> 2, tm = tile & 3;
  const u16* Ab = yh + ((size_t)b * 512 + tn * 128) * 768;
  const u16* Bb = xh + ((size_t)b * 512 + tm * 128) * 768;
  int tid = threadIdx.x;
  int w = tid >> 6, l = tid & 63;
  int wr = (w >> 1) << 6, wc = (w & 1) << 6;
  f32x4 acc[4][4] = {};
  for (int k0 = 0; k0 < 768; k0 += 64) {
    #pragma unroll
    for (int q = 0; q < 4; ++q) {
      int slot = (q << 8) + tid;
      int row = slot >> 3, col = (slot & 7) << 3;
      uint4 va = *(const uint4*)(Ab + row * 768 + k0 + col);
      uint4 vb = *(const uint4*)(Bb + row * 768 + k0 + col);
      *(uint4*)((char*)As + slot * 16) = va;
      *(uint4*)((char*)Bs + slot * 16) = vb;
    }
    __syncthreads();
    #pragma unroll
    for (int kk = 0; kk < 64; kk += 32) {
      int cb = (kk + ((l >> 4) << 3)) * 2;
      short8 a[4], bb[4];
      #pragma unroll
      for (int i = 0; i < 4; ++i)
        a[i] = *(const short8*)((const char*)As + (wr + (i << 4) + (l & 15)) * 128 + cb);
      #pragma unroll
      for (int j = 0; j < 4; ++j)
        bb[j] = *(const short8*)((const char*)Bs + (wc + (j << 4) + (l & 15)) * 128 + cb);
      #pragma unroll
      for (int i = 0; i < 4; ++i)
        #pragma unroll
        for (int j = 0; j < 4; ++j)
          acc[i][j] = __builtin_amdgcn_mfma_f32_16x16x32_bf16(a[i], bb[j], acc[i][j], 0, 0, 0);
    }
    __syncthreads();
  }
  int n0 = (tn << 7) + wr, m0 = (tm << 7) + wc;
  #pragma unroll
  for (int i = 0; i < 4; ++i) {
    #pragma unroll
    for (int j = 0; j < 4; ++j) {
      int m = m0 + (j << 4) + (l & 15);
      int xpm = rdmask(xpad, b * 512 + m, st);
      #pragma unroll
      for (int r = 0; r < 4; ++r) {
        int n = n0 + (i << 4) + ((l >> 4) << 2) + r;
        float v = 2.8853901f * (1.0f - acc[i][j][r]);
        if (xpm | rdmask(ypad, b * 512 + n, st)) v = 30000.0f;
        Ct2[((size_t)(b * 512 + n) << 9) + m] = f2bf(v);
      }
    }
  }
}

// ---------------- cross-block per-batch barrier (agent-scope) ----------------
__device__ __forceinline__ void batch_barrier(int* cnt, int target) {
  __syncthreads();
  if (threadIdx.x == 0) {
    __hip_atomic_fetch_add(cnt, 1, __ATOMIC_RELEASE, __HIP_MEMORY_SCOPE_AGENT);
    while (__hip_atomic_load(cnt, __ATOMIC_ACQUIRE, __HIP_MEMORY_SCOPE_AGENT) < target)
      __builtin_amdgcn_s_sleep(1);
  }
  __syncthreads();
}

// ---------------- IPOT in log2 space, 4 blocks per batch ----------------
// XCD co-location: b = bid&63, p = bid>>6 -> batch b's parts at bids {b,64+b,128+b,192+b},
// all == b (mod 8) -> same XCD under round-robin dispatch. Block owns rows [p*128, p*128+128).
__global__ __launch_bounds__(1024) void k_ipot4(const u16* __restrict__ Ct2,
                                                const u8* __restrict__ xpad, const u8* __restrict__ ypad,
                                                const int* __restrict__ flags,
                                                int* __restrict__ gcount, float* __restrict__ c_part,
                                                float* __restrict__ fin_part,
                                                float* __restrict__ ot) {
  int bid = blockIdx.x;
  int b = bid & 63, p = bid >> 6;
  int tid = threadIdx.x;
  int w = tid >> 6, l = tid & 63;
  int st = flags[0];
  __shared__ __align__(16) float lv[512], sig[512], xmk[512], ymk[512];
  __shared__ __align__(16) float lu[128], rr[128];
  __shared__ __align__(16) float cpart[16][512];
  __shared__ float redw[16];
  __shared__ int cnti[2];
  if (tid < 2) cnti[tid] = 0;
  __syncthreads();
  if (tid < 512) {
    int xp = rdmask(xpad, (b << 9) + tid, st) ? 1 : 0;
    int yp = rdmask(ypad, (b << 9) + tid, st) ? 1 : 0;
    xmk[tid] = xp ? 1e4f : 0.f;
    ymk[tid] = yp ? 1e4f : 0.f;
    lv[tid] = 0.f;
    atomicAdd(&cnti[0], 1 - xp);
    atomicAdd(&cnti[1], 1 - yp);
  }
  if (tid < 128) lu[tid] = 0.f;
  __syncthreads();
  float xl = (float)cnti[0], yl = (float)cnti[1];
  if (tid < 512) sig[tid] = (xmk[tid] > 0.f) ? 0.f : (1.0f / xl);
  __syncthreads();
  const int base_n = p << 7;
  const u16* Cb = Ct2 + ((size_t)b << 18) + ((size_t)base_n << 9);
  int* cnt_b = gcount + (b << 6);
  float* cp_b = c_part + ((size_t)b << 12);     // per batch: 2 parities * 4 parts * 512

  for (int it = 1; it <= 50; ++it) {
    float nt1 = -(float)it;
    int par = it & 1;
    float lvl[8], sgl[8];
    {
      const float4* p1 = (const float4*)&lv[l << 3];
      const float4* p2 = (const float4*)&sig[l << 3];
      float4 a0 = p1[0], a1 = p1[1], c0 = p2[0], c1 = p2[1];
      lvl[0]=a0.x; lvl[1]=a0.y; lvl[2]=a0.z; lvl[3]=a0.w;
      lvl[4]=a1.x; lvl[5]=a1.y; lvl[6]=a1.z; lvl[7]=a1.w;
      sgl[0]=c0.x; sgl[1]=c0.y; sgl[2]=c0.z; sgl[3]=c0.w;
      sgl[4]=c1.x; sgl[5]=c1.y; sgl[6]=c1.z; sgl[7]=c1.w;
    }
    // pass 1: rr[n] = sum_m exp2(lu[n]+lv[m]-t*C) * sig[m]   (own 128 rows)
    #pragma unroll
    for (int q = 0; q < 8; ++q) {
      int nl = (q << 4) | w;
      float lun = lu[nl];
      float bj[8];
      #pragma unroll
      for (int j = 0; j < 8; ++j) bj[j] = lun + lvl[j];
      const uint4 cv = *(const uint4*)(Cb + ((size_t)nl << 9) + (l << 3));
      float acc = 0.f;
      acc = fmaf(exp2_(fmaf(bflo(cv.x), nt1, bj[0])), sgl[0], acc);
      acc = fmaf(exp2_(fmaf(bfhi(cv.x), nt1, bj[1])), sgl[1], acc);
      acc = fmaf(exp2_(fmaf(bflo(cv.y), nt1, bj[2])), sgl[2], acc);
      acc = fmaf(exp2_(fmaf(bfhi(cv.y), nt1, bj[3])), sgl[3], acc);
      acc = fmaf(exp2_(fmaf(bflo(cv.z), nt1, bj[4])), sgl[4], acc);
      acc = fmaf(exp2_(fmaf(bfhi(cv.z), nt1, bj[5])), sgl[5], acc);
      acc = fmaf(exp2_(fmaf(bflo(cv.w), nt1, bj[6])), sgl[6], acc);
      acc = fmaf(exp2_(fmaf(bfhi(cv.w), nt1, bj[7])), sgl[7], acc);
      #pragma unroll
      for (int off = 32; off; off >>= 1) acc += __shfl_down(acc, off);
      if (l == 0) rr[nl] = acc;
    }
    __syncthreads();
    if (tid < 128) {
      float dv = 1.0f / fmaf(yl, rr[tid], ymk[base_n + tid]);
      lu[tid] += log2_(dv);   // fold delta into lu
    }
    __syncthreads();
    // pass 2: partial c[m] = sum_{own n} exp2(lu'[n]+lv[m]-t*C)
    float ca[8] = {0,0,0,0,0,0,0,0};
    #pragma unroll
    for (int q = 0; q < 8; ++q) {
      int nl = (q << 4) | w;
      float lun = lu[nl];
      float bj[8];
      #pragma unroll
      for (int j = 0; j < 8; ++j) bj[j] = lun + lvl[j];
      const uint4 cv = *(const uint4*)(Cb + ((size_t)nl << 9) + (l << 3));
      ca[0] += exp2_(fmaf(bflo(cv.x), nt1, bj[0]));
      ca[1] += exp2_(fmaf(bfhi(cv.x), nt1, bj[1]));
      ca[2] += exp2_(fmaf(bflo(cv.y), nt1, bj[2]));
      ca[3] += exp2_(fmaf(bfhi(cv.y), nt1, bj[3]));
      ca[4] += exp2_(fmaf(bflo(cv.z), nt1, bj[4]));
      ca[5] += exp2_(fmaf(bfhi(cv.z), nt1, bj[5]));
      ca[6] += exp2_(fmaf(bflo(cv.w), nt1, bj[6]));
      ca[7] += exp2_(fmaf(bfhi(cv.w), nt1, bj[7]));
    }
    {
      float4* dp = (float4*)&cpart[w][l << 3];
      float4 v0, v1;
      v0.x=ca[0]; v0.y=ca[1]; v0.z=ca[2]; v0.w=ca[3];
      v1.x=ca[4]; v1.y=ca[5]; v1.z=ca[6]; v1.w=ca[7];
      dp[0] = v0; dp[1] = v1;
    }
    __syncthreads();
    float* slot = cp_b + (par << 11) + (p << 9);
    if (tid < 512) {
      float s = 0.f;
      #pragma unroll
      for (int ww = 0; ww < 16; ++ww) s += cpart[ww][tid];
      __hip_atomic_store(&slot[tid], s, __ATOMIC_RELAXED, __HIP_MEMORY_SCOPE_AGENT);
    }
    batch_barrier(&cnt_b[it - 1], 4);
    if (tid < 512) {
      const float* base = cp_b + (par << 11);
      float s = __hip_atomic_load(&base[tid], __ATOMIC_RELAXED, __HIP_MEMORY_SCOPE_AGENT);
      s += __hip_atomic_load(&base[512 + tid], __ATOMIC_RELAXED, __HIP_MEMORY_SCOPE_AGENT);
      s += __hip_atomic_load(&base[1024 + tid], __ATOMIC_RELAXED, __HIP_MEMORY_SCOPE_AGENT);
      s += __hip_atomic_load(&base[1536 + tid], __ATOMIC_RELAXED, __HIP_MEMORY_SCOPE_AGENT);
      float sg = 1.0f / fmaf(xl, s, xmk[tid]);
      sig[tid] = sg;
      lv[tid] += log2_(sg);
    }
    __syncthreads();
  }
  // final: partial dist = sum_{own n} exp2(lu+lv-50*Ct2) * (Ct2 * beta*ln2)
  float lvl[8];
  {
    const float4* p1 = (const float4*)&lv[l << 3];
    float4 a0 = p1[0], a1 = p1[1];
    lvl[0]=a0.x; lvl[1]=a0.y; lvl[2]=a0.z; lvl[3]=a0.w;
    lvl[4]=a1.x; lvl[5]=a1.y; lvl[6]=a1.z; lvl[7]=a1.w;
  }
  float accT = 0.f;
  #pragma unroll
  for (int q = 0; q < 8; ++q) {
    int nl = (q << 4) | w;
    float lun = lu[nl];
    float bj[8];
    #pragma unroll
    for (int j = 0; j < 8; ++j) bj[j] = lun + lvl[j];
    const uint4 cv = *(const uint4*)(Cb + ((size_t)nl << 9) + (l << 3));
    float rp = 0.f, c0;
    c0 = bflo(cv.x); rp = fmaf(exp2_(fmaf(c0, -50.f, bj[0])), c0, rp);
    c0 = bfhi(cv.x); rp = fmaf(exp2_(fmaf(c0, -50.f, bj[1])), c0, rp);
    c0 = bflo(cv.y); rp = fmaf(exp2_(fmaf(c0, -50.f, bj[2])), c0, rp);
    c0 = bfhi(cv.y); rp = fmaf(exp2_(fmaf(c0, -50.f, bj[3])), c0, rp);
    c0 = bflo(cv.z); rp = fmaf(exp2_(fmaf(c0, -50.f, bj[4])), c0, rp);
    c0 = bfhi(cv.z); rp = fmaf(exp2_(fmaf(c0, -50.f, bj[5])), c0, rp);
    c0 = bflo(cv.w); rp = fmaf(exp2_(fmaf(c0, -50.f, bj[6])), c0, rp);
    c0 = bfhi(cv.w); rp = fmaf(exp2_(fmaf(c0, -50.f, bj[7])), c0, rp);
    accT += rp;
  }
  #pragma unroll
  for (int off = 32; off; off >>= 1) accT += __shfl_down(accT, off);
  if (l == 0) redw[w] = accT;
  __syncthreads();
  if (tid == 0) {
    float s = 0.f;
    #pragma unroll
    for (int ww = 0; ww < 16; ++ww) s += redw[ww];
    __hip_atomic_store(&fin_part[(b << 2) + p], s, __ATOMIC_RELAXED, __HIP_MEMORY_SCOPE_AGENT);
  }
  batch_barrier(&cnt_b[50], 4);
  if (p == 0 && tid == 0) {
    float s = 0.f;
    #pragma unroll
    for (int pp = 0; pp < 4; ++pp)
      s += __hip_atomic_load(&fin_part[(b << 2) + pp], __ATOMIC_RELAXED, __HIP_MEMORY_SCOPE_AGENT);
    ot[b] = s * 0.34657359f;  // beta * ln2
  }
}

// ---------------- CRF llh: one block (1 wave) per batch ----------------
__global__ __launch_bounds__(64) void k_crf(const float* __restrict__ emis, const int* __restrict__ tags,
                                            const u8* __restrict__ mask, const int* __restrict__ flags,
                                            const float* __restrict__ startT, const float* __restrict__ endT,
                                            const float* __restrict__ trans, float* __restrict__ llh) {
  int b = blockIdx.x;
  int k = threadIdx.x;
  int st = flags[0];
  __shared__ float tr[441];
  for (int i = k; i < 441; i += 64) tr[i] = trans[i];
  __syncthreads();
  // numerator (parallel over t)
  float accs = 0.f; int cnt = 0;
  for (int t = k; t < 512; t += 64) {
    int mt = rdmask(mask, (t << 6) + b, st);
    cnt += mt;
    int tg = tags[(t << 6) + b];
    if (t == 0) {
      accs += startT[tg] + emis[(size_t)b * 21 + tg];
    } else if (mt) {
      int tgp = tags[((t - 1) << 6) + b];
      accs += tr[tgp * 21 + tg] + emis[((size_t)((t << 6) + b)) * 21 + tg];
    }
  }
  #pragma unroll
  for (int off = 32; off; off >>= 1) { accs += __shfl_down(accs, off); cnt += __shfl_down(cnt, off); }
  float numer = 0.f;
  if (k == 0) {
    int last = tags[((cnt - 1) << 6) + b];
    numer = accs + endT[last];
  }
  // forward recursion (lanes 0..20 hold states)
  int kc = (k < 21) ? k : 20;
  float s = startT[kc] + emis[(size_t)b * 21 + kc];
  for (int t = 1; t < 512; ++t) {
    float z[21];
    float zmax = -3.0e38f;
    #pragma unroll
    for (int j = 0; j < 21; ++j) {
      float sj = __shfl(s, j);
      z[j] = sj + tr[j * 21 + kc];
      zmax = fmaxf(zmax, z[j]);
    }
    float sum = 0.f;
    #pragma unroll
    for (int j = 0; j < 21; ++j) sum += exp2_((z[j] - zmax) * LOG2E);
    float ns = zmax + log2_(sum) * LN2 + emis[((size_t)((t << 6) + b)) * 21 + kc];
    s = rdmask(mask, (t << 6) + b, st) ? ns : s;
  }
  float f = (k < 21) ? (s + endT[kc]) : -3.0e38f;
  float m = f;
  #pragma unroll
  for (int off = 32; off; off >>= 1) m = fmaxf(m, __shfl_xor(m, off));
  float sum = (k < 21) ? exp2_((f - m) * LOG2E) : 0.f;
  #pragma unroll
  for (int off = 32; off; off >>= 1) sum += __shfl_xor(sum, off);
  float denom = m + log2_(sum) * LN2;
  if (k == 0) llh[b] = numer - denom;
}

// ---------------- finalize: out = sum_b (ot[b] - llh[b]) ----------------
__global__ __launch_bounds__(64) void k_finalize(const float* __restrict__ llh, const float* __restrict__ ot,
                                                 float* __restrict__ out) {
  int l = threadIdx.x;
  float v = ot[l] - llh[l];
  #pragma unroll
  for (int off = 32; off; off >>= 1) v += __shfl_down(v, off);
  if (l == 0) out[0] = v;
}

extern "C" void kernel_launch(void* const* d_in, const int* in_sizes, int n_in,
                              void* d_out, int out_size, void* d_ws, size_t ws_size,
                              hipStream_t stream) {
  const float* emis  = (const float*)d_in[0];
  const float* txt   = (const float*)d_in[1];
  const float* img   = (const float*)d_in[2];
  const float* startT= (const float*)d_in[3];
  const float* endT  = (const float*)d_in[4];
  const float* trans = (const float*)d_in[5];
  const int*  tags   = (const int*)d_in[6];
  const u8* cmask = (const u8*)d_in[7];
  const u8* xpad  = (const u8*)d_in[8];
  const u8* ypad  = (const u8*)d_in[9];
  char* wsb = (char*)d_ws;
  u16* xh  = (u16*)wsb;                          // 50331648 B
  u16* yh  = (u16*)(wsb + 50331648ll);           // 50331648 B
  u16* Ct2 = (u16*)(wsb + 100663296ll);          // 33554432 B
  float* ot    = (float*)(wsb + 134217728ll);    // 64
  float* llh   = ot + 64;                        // 64
  int*  flags  = (int*)(llh + 64);
  int*  gcount = (int*)(wsb + 134218752ll);      // 64*64 ints = 16384 B
  float* c_part= (float*)(wsb + 134235136ll);    // 64*2*4*512 f32 = 1 MB
  float* fin_part=(float*)(wsb + 135283712ll);   // 64*4 f32
  float* out = (float*)d_out;

  hipMemsetAsync(gcount, 0, 64 * 64 * sizeof(int), stream);
  hipLaunchKernelGGL(k_detect, dim3(1), dim3(1), 0, stream, (const u32*)cmask, flags);
  hipLaunchKernelGGL(k_normalize, dim3(16384), dim3(256), 0, stream, txt, img, xh, yh);
  hipLaunchKernelGGL(k_cost_gemm, dim3(1024), dim3(256), 0, stream, xh, yh, xpad, ypad, flags, Ct2);
  hipLaunchKernelGGL(k_crf, dim3(64), dim3(64), 0, stream, emis, tags, cmask, flags, startT, endT, trans, llh);
  hipLaunchKernelGGL(k_ipot4, dim3(256), dim3(1024), 0, stream, Ct2, xpad, ypad, flags, gcount, c_part, fin_part, ot);
  hipLaunchKernelGGL(k_finalize, dim3(1), dim3(64), 0, stream, llh, ot, out);
}